// Round 8
// baseline (98637.030 us; speedup 1.0000x reference)
//
#include <hip/hip_runtime.h>
#include <cstdint>
#include <cstddef>

#define LSTM_D  512
#define LSTM_4D 2048
#define LSTM_L  32768
#define REC_G   64               // workgroups; each owns 8 d-indices
#define REC_DPW 8
#define N_REPL  8                // h-buffer replicas (channel spreading)

typedef float f32x4 __attribute__((ext_vector_type(4)));  // native v4f32 for asm "v"

// Workspace layout:
//   ws +      0 : hb, 8 replicas x (2 buffers x 256 f32x4) = 64 KB
//                 replica r, buffer B, PHYSICAL slot s at hb[r*512 + B*256 + s]
//                 Logical flit f = {h[2f], h[2f+1], tag, 0} lives at physical
//                 slot phys(f) = (f&7)*32 + (f>>3).  Instruction-contiguous
//                 permutation: consumer spin-load instruction j reads slots
//                 j*32..j*32+31 = 512 B contiguous = 4 lines.
//   ws +  65536 : cbuf (512 f) c carry between chunk launches
//   ws + 131072 : wpack (64 wg * 4096 float4 = 4 MB) swizzled Wh
//   ws + 131072 + 4 MB : xbuf (C*2048 f) x-projection chunk, GATE-INTERLEAVED:
//                 xbuf[t][d*4 + g] so one dwordx4 per d fetches {i,f,g,o}
#define WS_CBUF_OFF  65536
#define WS_WPACK_OFF 131072
#define WS_XBUF_OFF  (131072 + (size_t)REC_G * 4096 * sizeof(float4))

// ---------------------------------------------------------------------------
// GEMM: xbuf[C][2048] = xs_chunk[C][512] @ Wi[512][2048] + b
// Output stored gate-interleaved (pos = dd*4 + g for col = g*512 + dd) so
// lstm_rec reads one float4 {i,f,g,o} per d.  (Verified correct in r6/r7.)
// ---------------------------------------------------------------------------
__global__ __launch_bounds__(256)
void gemm_xproj(const float* __restrict__ A,
                const float* __restrict__ B,
                const float* __restrict__ bias,
                float* __restrict__ C)
{
    __shared__ float As[16][64];
    __shared__ float Bs[16][64];
    const int tid  = threadIdx.x;
    const int row0 = blockIdx.y * 64;
    const int col0 = blockIdx.x * 64;
    const int tx   = tid & 15;
    const int ty   = tid >> 4;
    const int lr   = tid >> 2;
    const int lk4  = (tid & 3) * 4;
    const int bk   = tid >> 4;
    const int bc4  = (tid & 15) * 4;

    float acc[4][4] = {};

    for (int k0 = 0; k0 < LSTM_D; k0 += 16) {
        float4 av = *(const float4*)(A + (size_t)(row0 + lr) * LSTM_D + k0 + lk4);
        float4 bv = *(const float4*)(B + (size_t)(k0 + bk) * LSTM_4D + col0 + bc4);
        __syncthreads();
        As[lk4 + 0][lr] = av.x;
        As[lk4 + 1][lr] = av.y;
        As[lk4 + 2][lr] = av.z;
        As[lk4 + 3][lr] = av.w;
        *(float4*)(&Bs[bk][bc4]) = bv;
        __syncthreads();
#pragma unroll
        for (int k = 0; k < 16; ++k) {
            float4 a4 = *(const float4*)(&As[k][ty * 4]);
            float4 b4 = *(const float4*)(&Bs[k][tx * 4]);
            acc[0][0] = fmaf(a4.x, b4.x, acc[0][0]);
            acc[0][1] = fmaf(a4.x, b4.y, acc[0][1]);
            acc[0][2] = fmaf(a4.x, b4.z, acc[0][2]);
            acc[0][3] = fmaf(a4.x, b4.w, acc[0][3]);
            acc[1][0] = fmaf(a4.y, b4.x, acc[1][0]);
            acc[1][1] = fmaf(a4.y, b4.y, acc[1][1]);
            acc[1][2] = fmaf(a4.y, b4.z, acc[1][2]);
            acc[1][3] = fmaf(a4.y, b4.w, acc[1][3]);
            acc[2][0] = fmaf(a4.z, b4.x, acc[2][0]);
            acc[2][1] = fmaf(a4.z, b4.y, acc[2][1]);
            acc[2][2] = fmaf(a4.z, b4.z, acc[2][2]);
            acc[2][3] = fmaf(a4.z, b4.w, acc[2][3]);
            acc[3][0] = fmaf(a4.w, b4.x, acc[3][0]);
            acc[3][1] = fmaf(a4.w, b4.y, acc[3][1]);
            acc[3][2] = fmaf(a4.w, b4.z, acc[3][2]);
            acc[3][3] = fmaf(a4.w, b4.w, acc[3][3]);
        }
    }

    float4 bb = *(const float4*)(bias + col0 + tx * 4);
    float bbv[4] = {bb.x, bb.y, bb.z, bb.w};
#pragma unroll
    for (int i = 0; i < 4; ++i) {
#pragma unroll
        for (int j = 0; j < 4; ++j) {
            const int col = col0 + tx * 4 + j;
            const int dd  = col & (LSTM_D - 1);
            const int g   = col >> 9;
            C[(size_t)(row0 + ty * 4 + i) * LSTM_4D + dd * 4 + g] =
                acc[i][j] + bbv[j];
        }
    }
}

// ---------------------------------------------------------------------------
// Swizzled Wh pack (unchanged layout; see lstm_rec comment).
// ---------------------------------------------------------------------------
__global__ __launch_bounds__(256)
void pack_wh(const float* __restrict__ Wh, float4* __restrict__ wp)
{
    const int wg  = blockIdx.x;
    const int tid = threadIdx.x;
    for (int s = 0; s < 16; ++s) {
        const int gidx  = s * 256 + tid;
        const int wave  = gidx >> 10;
        const int lane  = (gidx >> 4) & 63;
        const int mphys = gidx & 15;
        const int m     = mphys ^ (lane & 15);
        const int g     = m >> 2;
        const int gi    = m & 3;
        const int p     = lane >> 1;
        const int d     = wg * REC_DPW + wave * 2 + (lane & 1);
        const int k     = p * 16 + gi * 4;
        float4 v;
        v.x = Wh[(size_t)(k + 0) * LSTM_4D + g * LSTM_D + d];
        v.y = Wh[(size_t)(k + 1) * LSTM_4D + g * LSTM_D + d];
        v.z = Wh[(size_t)(k + 2) * LSTM_4D + g * LSTM_D + d];
        v.w = Wh[(size_t)(k + 3) * LSTM_4D + g * LSTM_D + d];
        wp[(size_t)wg * 4096 + gidx] = v;
    }
}

// ---------------------------------------------------------------------------
// Init tagged h replicas in the PERMUTED layout. Buffer 1 = h0 with tag -1
// (step 0 reads buffer (0-1)&1 = 1 expecting tag -1); buffer 0 tag = -2.
// Logical flit j lands at physical slot (j&7)*32 + (j>>3).
// ---------------------------------------------------------------------------
__global__ void init_h(const float* __restrict__ h0, f32x4* __restrict__ hb)
{
    const int r = blockIdx.x;                // replica 0..7
    const int j = threadIdx.x;               // logical flit 0..255
    const int s = (j & 7) * 32 + (j >> 3);   // physical slot
    f32x4 a; a.x = h0[2 * j]; a.y = h0[2 * j + 1]; a.z = -1.0f; a.w = 0.0f;
    f32x4 z; z.x = 0.0f;      z.y = 0.0f;          z.z = -2.0f; z.w = 0.0f;
    hb[r * 512 + 256 + s] = a;
    hb[r * 512 + s]       = z;
}

// ---------------------------------------------------------------------------
// Coherent 16B ops straight to/from the coherence point (sc0 sc1 bypass
// L1/L2): tag travels in the same 16B flit as the data.  r3-verified form:
// vmcnt(0) inside every poll -- no loads ever left in flight (r5 lesson).
// Instruction-contiguous layout: base = slot p, the 8 loads step by 512 B.
// Load %N returns logical flit p*8 + N.
// ---------------------------------------------------------------------------
__device__ inline void load8_cohere(const f32x4* p, f32x4 h[8])
{
    asm volatile(
        "global_load_dwordx4 %0, %8, off sc0 sc1\n\t"
        "global_load_dwordx4 %1, %8, off offset:512 sc0 sc1\n\t"
        "global_load_dwordx4 %2, %8, off offset:1024 sc0 sc1\n\t"
        "global_load_dwordx4 %3, %8, off offset:1536 sc0 sc1\n\t"
        "global_load_dwordx4 %4, %8, off offset:2048 sc0 sc1\n\t"
        "global_load_dwordx4 %5, %8, off offset:2560 sc0 sc1\n\t"
        "global_load_dwordx4 %6, %8, off offset:3072 sc0 sc1\n\t"
        "global_load_dwordx4 %7, %8, off offset:3584 sc0 sc1\n\t"
        "s_waitcnt vmcnt(0)"
        : "=&v"(h[0]), "=&v"(h[1]), "=&v"(h[2]), "=&v"(h[3]),
          "=&v"(h[4]), "=&v"(h[5]), "=&v"(h[6]), "=&v"(h[7])
        : "v"(p)
        : "memory");
}

__device__ inline void store_cohere(f32x4* p, f32x4 v)
{
    asm volatile("global_store_dwordx4 %0, %1, off sc0 sc1"
                 :: "v"(p), "v"(v) : "memory");
}

// Normal-cached load of the gate-interleaved xp quad {i,f,g,o} for this d.
// Issued before the spin; the spin's first vmcnt(0) drains it. tie1 pins
// the use after that drain (volatile asm blocks keep relative order).
// Verified correct in r6/r7.
__device__ inline void issue1_load(const float* p, f32x4* v)
{
    asm volatile("global_load_dwordx4 %0, %1, off"
                 : "=&v"(*v) : "v"(p) : "memory");
}

__device__ inline void tie1(f32x4* v)
{
    asm volatile("" : "+v"(*v));
    __builtin_amdgcn_sched_barrier(0);
}

__device__ inline void drain_vm0(void)
{
    asm volatile("s_waitcnt vmcnt(0)" ::: "memory");
}

// Fast activations: v_exp + v_rcp forms (verified absmax 3.9e-3 in r6/r7,
// threshold 1.8e-2).
__device__ inline float fast_sig(float x)
{
    return __builtin_amdgcn_rcpf(1.0f + __expf(-x));
}
__device__ inline float fast_tanh(float x)
{
    return 1.0f - 2.0f * __builtin_amdgcn_rcpf(1.0f + __expf(2.0f * x));
}

// ---------------------------------------------------------------------------
// Barrier-free persistent recurrent kernel.
//
// r8 = r3 (best verified, 67.0 ms) + two micro-wins verified in r6/r7:
//   * gate-interleaved xq: ONE cached dwordx4 per step instead of 4
//     scattered scalar loads; issued pre-spin, drained by the spin's
//     vmcnt(0).
//   * fast v_exp+v_rcp activations on the 2-lane critical tail.
// Weights STAY IN LDS (r6/r7 proved the compiler will not keep them in
// VGPRs: plain loads get rematerialized, volatile-asm results get spilled;
// both put per-step global traffic on the critical path).
// Spin protocol byte-identical to r3: tag-in-flit self-validating spin with
// vmcnt(0) per poll, 8 replicas, permuted slots, publish-first.
// Buffer reuse safety unchanged: a wave publishes t only after consuming
// t-1, so all-t-tags visible implies all t-1 reads retired.
// ---------------------------------------------------------------------------
__global__ __launch_bounds__(256, 1)
void lstm_rec(const float4* __restrict__ wp,
              const float* __restrict__ xp,    // chunk's [steps][2048] gate-interleaved
              const float* __restrict__ c0,
              float* __restrict__ out,
              f32x4* __restrict__ hb,          // 8 x 2 x 256 tagged pairs
              float* __restrict__ cbuf,        // 512 floats
              int t0, int steps)
{
    __shared__ float4 W[4096];                 // exactly 64 KB

    const int wg   = blockIdx.x;
    const int tid  = threadIdx.x;
    const int wave = tid >> 6;
    const int lane = tid & 63;
    const int p    = lane >> 1;
    const int d    = wg * REC_DPW + wave * 2 + (lane & 1);
    const int d0   = wg * REC_DPW + wave * 2;  // wave's first d
    const int mybase = wave * 1024 + lane * 16;
    const int lx   = lane & 15;
    const int fj   = wg * 4 + wave;            // this wave's logical flit
    const int pfj  = (fj & 7) * 32 + (fj >> 3);// physical slot of that flit
    const int myrep = wg & 7;                  // consumer replica

    // One-time LDS weight fill (coalesced 64 KB copy), the only barrier.
#pragma unroll
    for (int s = 0; s < 16; ++s)
        W[s * 256 + tid] = wp[(size_t)wg * 4096 + s * 256 + tid];
    __syncthreads();

    float c_val = 0.f;
    if (lane < 2) c_val = (t0 == 0) ? c0[d] : cbuf[d];

    int dead = 0;

    for (int ts = 0; ts < steps; ++ts) {
        const int t = t0 + ts;
        const float exp_tag = (float)(t - 1);
        const f32x4* src = hb + myrep * 512 + ((t + 1) & 1) * 256 + p;

        // xp prefetch: one dwordx4 {i,f,g,o}; all lanes load (2 distinct
        // in-bounds addresses per wave), only lanes 0/1 consume.
        f32x4 xq;
        issue1_load(xp + (size_t)ts * LSTM_4D + (size_t)d * 4, &xq);

        // Tagged spin-consume from replica wg&7, buffer (t-1)&1.
        f32x4 hp[8];
        int tries = 0;
        for (;;) {
            load8_cohere(src, hp);
            bool ok = (hp[0].z == exp_tag) & (hp[1].z == exp_tag) &
                      (hp[2].z == exp_tag) & (hp[3].z == exp_tag) &
                      (hp[4].z == exp_tag) & (hp[5].z == exp_tag) &
                      (hp[6].z == exp_tag) & (hp[7].z == exp_tag);
            if (dead || (__ballot(ok) == ~0ull)) break;
            if (++tries > (1 << 16)) { dead = 1; break; }
        }

        float h[16];
#pragma unroll
        for (int j = 0; j < 8; ++j) {
            h[2 * j]     = hp[j].x;
            h[2 * j + 1] = hp[j].y;
        }

        // FMA from LDS weights (xor-swizzled, bank-uniform).
        float a0 = 0.f, a1 = 0.f, a2 = 0.f, a3 = 0.f;
#pragma unroll
        for (int gi = 0; gi < 4; ++gi) {
            float4 w0 = W[mybase + ((0 * 4 + gi) ^ lx)];
            float4 w1 = W[mybase + ((1 * 4 + gi) ^ lx)];
            float4 w2 = W[mybase + ((2 * 4 + gi) ^ lx)];
            float4 w3 = W[mybase + ((3 * 4 + gi) ^ lx)];
            const float h0v = h[gi * 4 + 0], h1v = h[gi * 4 + 1];
            const float h2v = h[gi * 4 + 2], h3v = h[gi * 4 + 3];
            a0 = fmaf(h0v, w0.x, a0); a0 = fmaf(h1v, w0.y, a0);
            a0 = fmaf(h2v, w0.z, a0); a0 = fmaf(h3v, w0.w, a0);
            a1 = fmaf(h0v, w1.x, a1); a1 = fmaf(h1v, w1.y, a1);
            a1 = fmaf(h2v, w1.z, a1); a1 = fmaf(h3v, w1.w, a1);
            a2 = fmaf(h0v, w2.x, a2); a2 = fmaf(h1v, w2.y, a2);
            a2 = fmaf(h2v, w2.z, a2); a2 = fmaf(h3v, w2.w, a2);
            a3 = fmaf(h0v, w3.x, a3); a3 = fmaf(h1v, w3.y, a3);
            a3 = fmaf(h2v, w3.z, a3); a3 = fmaf(h3v, w3.w, a3);
        }

        // Reduce over p (lane bits 1..5).
#pragma unroll
        for (int m = 2; m <= 32; m <<= 1) {
            a0 += __shfl_xor(a0, m, 64);
            a1 += __shfl_xor(a1, m, 64);
            a2 += __shfl_xor(a2, m, 64);
            a3 += __shfl_xor(a3, m, 64);
        }

        tie1(&xq);   // xq drained by the spin's vmcnt(0); tie before use

        float hval = 0.f;
        if (lane < 2) {
            float yi = xq.x + a0;
            float yf = xq.y + a1;
            float yg = xq.z + a2;
            float yo = xq.w + a3;
            float si = fast_sig(yi);
            float sf = fast_sig(yf);
            float so = fast_sig(yo);
            float tg = fast_tanh(yg);
            c_val = fmaf(sf, c_val, si * tg);
            hval  = so * fast_tanh(c_val);
        }
        const float h_other = __shfl_xor(hval, 1, 64);  // partner d's h

        // Publish FIRST (critical path), out store after. Lanes 0/1 each
        // write 4 replicas at the permuted slot.
        if (lane < 2) {
            f32x4 pub;
            pub.x = (lane == 0) ? hval : h_other;
            pub.y = (lane == 0) ? h_other : hval;
            pub.z = (float)t;
            pub.w = 0.0f;
            f32x4* dst = hb + (size_t)(lane * 4) * 512 + (t & 1) * 256 + pfj;
            store_cohere(dst + 0 * 512, pub);
            store_cohere(dst + 1 * 512, pub);
            store_cohere(dst + 2 * 512, pub);
            store_cohere(dst + 3 * 512, pub);
        }

        if (lane == 0)
            *(float2*)(out + (size_t)t * LSTM_D + d0) = make_float2(hval, h_other);
    }

    drain_vm0();
    if (lane < 2) cbuf[d] = c_val;   // c carry for next chunk launch
}

// ---------------------------------------------------------------------------
extern "C" void kernel_launch(void* const* d_in, const int* in_sizes, int n_in,
                              void* d_out, int out_size, void* d_ws, size_t ws_size,
                              hipStream_t stream)
{
    const float* xs = (const float*)d_in[0];   // [L, 512]
    const float* Wi = (const float*)d_in[1];   // [512, 2048]
    const float* Wh = (const float*)d_in[2];   // [512, 2048]
    const float* b  = (const float*)d_in[3];   // [2048]
    const float* c0 = (const float*)d_in[4];   // [512]
    const float* h0 = (const float*)d_in[5];   // [512]
    float* out = (float*)d_out;                // [L, 512]

    uint8_t* ws = (uint8_t*)d_ws;
    f32x4*  hb    = (f32x4*)ws;
    float*  cbuf  = (float*)(ws + WS_CBUF_OFF);
    float4* wpack = (float4*)(ws + WS_WPACK_OFF);
    float*  xbuf  = (float*)(ws + WS_XBUF_OFF);

    // Largest power-of-two chunk whose xbuf fits in the workspace.
    int C = LSTM_L;
    while (C > 64 &&
           WS_XBUF_OFF + (size_t)C * LSTM_4D * sizeof(float) > ws_size)
        C >>= 1;

    init_h<<<N_REPL, 256, 0, stream>>>(h0, hb);
    pack_wh<<<REC_G, 256, 0, stream>>>(Wh, wpack);

    const int nChunks = LSTM_L / C;
    for (int k = 0; k < nChunks; ++k) {
        dim3 ggrid(LSTM_4D / 64, C / 64);
        gemm_xproj<<<ggrid, 256, 0, stream>>>(xs + (size_t)k * C * LSTM_D,
                                              Wi, b, xbuf);
        lstm_rec<<<REC_G, 256, 0, stream>>>(wpack, xbuf, c0, out,
                                            hb, cbuf, k * C, C);
    }
}

// Round 11
// 56489.606 us; speedup vs baseline: 1.7461x; 1.7461x over previous
//
#include <hip/hip_runtime.h>
#include <cstdint>
#include <cstddef>

#define LSTM_D  512
#define LSTM_4D 2048
#define LSTM_L  32768
#define REC_G   64               // workgroups; each owns 8 d-indices
#define REC_DPW 8
#define N_REPL  8                // h-buffer replicas (channel spreading)

typedef float f32x4 __attribute__((ext_vector_type(4)));  // native v4f32 for asm "v"

// Workspace layout:
//   ws +      0 : hb, 8 replicas x (2 buffers x 256 f32x4) = 64 KB
//                 replica r, buffer B, PHYSICAL slot s at hb[r*512 + B*256 + s]
//                 Logical flit f = {h[2f], h[2f+1], tag, 0} lives at physical
//                 slot phys(f) = (f&7)*32 + (f>>3).  Instruction-contiguous
//                 permutation: consumer spin-load instruction j reads slots
//                 j*32..j*32+31 = 512 B contiguous = 4 lines.
//   ws +  65536 : cbuf (512 f) c carry between chunk launches
//   ws + 131072 : wpack (64 wg * 4096 float4 = 4 MB) swizzled Wh
//   ws + 131072 + 4 MB : xbuf (C*2048 f) x-projection chunk (r3 row layout)
#define WS_CBUF_OFF  65536
#define WS_WPACK_OFF 131072
#define WS_XBUF_OFF  (131072 + (size_t)REC_G * 4096 * sizeof(float4))

// ---------------------------------------------------------------------------
// GEMM: xbuf[C][2048] = xs_chunk[C][512] @ Wi[512][2048] + b
// EXACT r3 version (coalesced float4 stores, plain row layout).
// ---------------------------------------------------------------------------
__global__ __launch_bounds__(256)
void gemm_xproj(const float* __restrict__ A,
                const float* __restrict__ B,
                const float* __restrict__ bias,
                float* __restrict__ C)
{
    __shared__ float As[16][64];
    __shared__ float Bs[16][64];
    const int tid  = threadIdx.x;
    const int row0 = blockIdx.y * 64;
    const int col0 = blockIdx.x * 64;
    const int tx   = tid & 15;
    const int ty   = tid >> 4;
    const int lr   = tid >> 2;
    const int lk4  = (tid & 3) * 4;
    const int bk   = tid >> 4;
    const int bc4  = (tid & 15) * 4;

    float acc[4][4] = {};

    for (int k0 = 0; k0 < LSTM_D; k0 += 16) {
        float4 av = *(const float4*)(A + (size_t)(row0 + lr) * LSTM_D + k0 + lk4);
        float4 bv = *(const float4*)(B + (size_t)(k0 + bk) * LSTM_4D + col0 + bc4);
        __syncthreads();
        As[lk4 + 0][lr] = av.x;
        As[lk4 + 1][lr] = av.y;
        As[lk4 + 2][lr] = av.z;
        As[lk4 + 3][lr] = av.w;
        *(float4*)(&Bs[bk][bc4]) = bv;
        __syncthreads();
#pragma unroll
        for (int k = 0; k < 16; ++k) {
            float4 a4 = *(const float4*)(&As[k][ty * 4]);
            float4 b4 = *(const float4*)(&Bs[k][tx * 4]);
            acc[0][0] = fmaf(a4.x, b4.x, acc[0][0]);
            acc[0][1] = fmaf(a4.x, b4.y, acc[0][1]);
            acc[0][2] = fmaf(a4.x, b4.z, acc[0][2]);
            acc[0][3] = fmaf(a4.x, b4.w, acc[0][3]);
            acc[1][0] = fmaf(a4.y, b4.x, acc[1][0]);
            acc[1][1] = fmaf(a4.y, b4.y, acc[1][1]);
            acc[1][2] = fmaf(a4.y, b4.z, acc[1][2]);
            acc[1][3] = fmaf(a4.y, b4.w, acc[1][3]);
            acc[2][0] = fmaf(a4.z, b4.x, acc[2][0]);
            acc[2][1] = fmaf(a4.z, b4.y, acc[2][1]);
            acc[2][2] = fmaf(a4.z, b4.z, acc[2][2]);
            acc[2][3] = fmaf(a4.z, b4.w, acc[2][3]);
            acc[3][0] = fmaf(a4.w, b4.x, acc[3][0]);
            acc[3][1] = fmaf(a4.w, b4.y, acc[3][1]);
            acc[3][2] = fmaf(a4.w, b4.z, acc[3][2]);
            acc[3][3] = fmaf(a4.w, b4.w, acc[3][3]);
        }
    }

    float4 bb = *(const float4*)(bias + col0 + tx * 4);
#pragma unroll
    for (int i = 0; i < 4; ++i) {
        float4 o;
        o.x = acc[i][0] + bb.x;
        o.y = acc[i][1] + bb.y;
        o.z = acc[i][2] + bb.z;
        o.w = acc[i][3] + bb.w;
        *(float4*)(C + (size_t)(row0 + ty * 4 + i) * LSTM_4D + col0 + tx * 4) = o;
    }
}

// ---------------------------------------------------------------------------
// Swizzled Wh pack (unchanged; see lstm_rec layout comment).
// ---------------------------------------------------------------------------
__global__ __launch_bounds__(256)
void pack_wh(const float* __restrict__ Wh, float4* __restrict__ wp)
{
    const int wg  = blockIdx.x;
    const int tid = threadIdx.x;
    for (int s = 0; s < 16; ++s) {
        const int gidx  = s * 256 + tid;
        const int wave  = gidx >> 10;
        const int lane  = (gidx >> 4) & 63;
        const int mphys = gidx & 15;
        const int m     = mphys ^ (lane & 15);
        const int g     = m >> 2;
        const int gi    = m & 3;
        const int p     = lane >> 1;
        const int d     = wg * REC_DPW + wave * 2 + (lane & 1);
        const int k     = p * 16 + gi * 4;
        float4 v;
        v.x = Wh[(size_t)(k + 0) * LSTM_4D + g * LSTM_D + d];
        v.y = Wh[(size_t)(k + 1) * LSTM_4D + g * LSTM_D + d];
        v.z = Wh[(size_t)(k + 2) * LSTM_4D + g * LSTM_D + d];
        v.w = Wh[(size_t)(k + 3) * LSTM_4D + g * LSTM_D + d];
        wp[(size_t)wg * 4096 + gidx] = v;
    }
}

// ---------------------------------------------------------------------------
// Init tagged h replicas in the PERMUTED layout. Buffer 1 = h0 with tag -1
// (step 0 reads buffer (0-1)&1 = 1 expecting tag -1); buffer 0 tag = -2.
// Logical flit j lands at physical slot (j&7)*32 + (j>>3).
// ---------------------------------------------------------------------------
__global__ void init_h(const float* __restrict__ h0, f32x4* __restrict__ hb)
{
    const int r = blockIdx.x;                // replica 0..7
    const int j = threadIdx.x;               // logical flit 0..255
    const int s = (j & 7) * 32 + (j >> 3);   // physical slot
    f32x4 a; a.x = h0[2 * j]; a.y = h0[2 * j + 1]; a.z = -1.0f; a.w = 0.0f;
    f32x4 z; z.x = 0.0f;      z.y = 0.0f;          z.z = -2.0f; z.w = 0.0f;
    hb[r * 512 + 256 + s] = a;
    hb[r * 512 + s]       = z;
}

// ---------------------------------------------------------------------------
// Coherent 16B ops straight to/from the coherence point (sc0 sc1 bypass
// L1/L2): tag travels in the same 16B flit as the data.  r3-verified form:
// vmcnt(0) inside every poll -- no loads ever left in flight (r5 lesson).
// Instruction-contiguous layout: base = slot p, the 8 loads step by 512 B.
// Load %N returns logical flit p*8 + N.
// ---------------------------------------------------------------------------
__device__ inline void load8_cohere(const f32x4* p, f32x4 h[8])
{
    asm volatile(
        "global_load_dwordx4 %0, %8, off sc0 sc1\n\t"
        "global_load_dwordx4 %1, %8, off offset:512 sc0 sc1\n\t"
        "global_load_dwordx4 %2, %8, off offset:1024 sc0 sc1\n\t"
        "global_load_dwordx4 %3, %8, off offset:1536 sc0 sc1\n\t"
        "global_load_dwordx4 %4, %8, off offset:2048 sc0 sc1\n\t"
        "global_load_dwordx4 %5, %8, off offset:2560 sc0 sc1\n\t"
        "global_load_dwordx4 %6, %8, off offset:3072 sc0 sc1\n\t"
        "global_load_dwordx4 %7, %8, off offset:3584 sc0 sc1\n\t"
        "s_waitcnt vmcnt(0)"
        : "=&v"(h[0]), "=&v"(h[1]), "=&v"(h[2]), "=&v"(h[3]),
          "=&v"(h[4]), "=&v"(h[5]), "=&v"(h[6]), "=&v"(h[7])
        : "v"(p)
        : "memory");
}

__device__ inline void store_cohere(f32x4* p, f32x4 v)
{
    asm volatile("global_store_dwordx4 %0, %1, off sc0 sc1"
                 :: "v"(p), "v"(v) : "memory");
}

// Fast activations: v_exp + v_rcp forms. The ONLY graft on the r3 base.
// Pure VALU, no memory-system interaction; numerics verified in r6/r7/r8
// (absmax 3.9e-3, threshold 1.8e-2, identical to libm baseline).
__device__ inline float fast_sig(float x)
{
    return __builtin_amdgcn_rcpf(1.0f + __expf(-x));
}
__device__ inline float fast_tanh(float x)
{
    return 1.0f - 2.0f * __builtin_amdgcn_rcpf(1.0f + __expf(2.0f * x));
}

// ---------------------------------------------------------------------------
// Barrier-free persistent recurrent kernel.
//
// r9-resubmit (x2, broker timeouts) = EXACT r3 (best verified, 67.0 ms;
// 31.7 ms/chunk) with ONE graft: fast v_exp+v_rcp activations on the
// 2-lane critical tail.
// Explicitly REVERTED from r6-r8 (all regressed to 94-99 ms):
//   * gate-interleaved xbuf + all-lane asm dwordx4 xq prefetch + tie1
//     (the shared suspect cluster: FETCH/step doubled, ~2.6x spin
//     iterations, +1 us/step in every round that carried it)
//   * register-resident weights (compiler remats plain loads / spills
//     volatile-asm results; both put global traffic on the critical path)
// Spin protocol: tag-in-flit self-validating spin with vmcnt(0) per poll,
// 8 replicas, permuted slots, publish-first. Buffer reuse safety: a wave
// publishes t only after consuming t-1, so all-t-tags visible implies all
// t-1 reads retired.
// ---------------------------------------------------------------------------
__global__ __launch_bounds__(256, 1)
void lstm_rec(const float4* __restrict__ wp,
              const float* __restrict__ xp,    // chunk's [steps][2048] row layout
              const float* __restrict__ c0,
              float* __restrict__ out,
              f32x4* __restrict__ hb,          // 8 x 2 x 256 tagged pairs
              float* __restrict__ cbuf,        // 512 floats
              int t0, int steps)
{
    __shared__ float4 W[4096];                 // exactly 64 KB

    const int wg   = blockIdx.x;
    const int tid  = threadIdx.x;
    const int wave = tid >> 6;
    const int lane = tid & 63;
    const int p    = lane >> 1;
    const int d    = wg * REC_DPW + wave * 2 + (lane & 1);
    const int d0   = wg * REC_DPW + wave * 2;  // wave's first d
    const int mybase = wave * 1024 + lane * 16;
    const int lx   = lane & 15;
    const int fj   = wg * 4 + wave;            // this wave's logical flit
    const int pfj  = (fj & 7) * 32 + (fj >> 3);// physical slot of that flit
    const int myrep = wg & 7;                  // consumer replica

    // One-time LDS weight fill (coalesced 64 KB copy), the only barrier.
#pragma unroll
    for (int s = 0; s < 16; ++s)
        W[s * 256 + tid] = wp[(size_t)wg * 4096 + s * 256 + tid];
    __syncthreads();

    float c_val = 0.f;
    if (lane < 2) c_val = (t0 == 0) ? c0[d] : cbuf[d];

    int dead = 0;

    for (int ts = 0; ts < steps; ++ts) {
        const int t = t0 + ts;

        // xp prefetch (independent of h), lanes 0/1 only -- r3-exact.
        float xpi = 0.f, xpf = 0.f, xpg = 0.f, xpo = 0.f;
        if (lane < 2) {
            const float* row = xp + (size_t)ts * LSTM_4D + d;
            xpi = row[0];
            xpf = row[LSTM_D];
            xpg = row[2 * LSTM_D];
            xpo = row[3 * LSTM_D];
        }

        // Tagged spin-consume from replica wg&7, buffer (t-1)&1. Base slot
        // is p (16 B); the 8 loads step 512 B, returning logical flits
        // p*8 .. p*8+7.
        const float  exp_tag = (float)(t - 1);
        const f32x4* src = hb + myrep * 512 + ((t + 1) & 1) * 256 + p;
        f32x4 hp[8];
        int tries = 0;
        for (;;) {
            load8_cohere(src, hp);
            bool ok = (hp[0].z == exp_tag) & (hp[1].z == exp_tag) &
                      (hp[2].z == exp_tag) & (hp[3].z == exp_tag) &
                      (hp[4].z == exp_tag) & (hp[5].z == exp_tag) &
                      (hp[6].z == exp_tag) & (hp[7].z == exp_tag);
            if (dead || (__ballot(ok) == ~0ull)) break;
            if (++tries > (1 << 16)) { dead = 1; break; }
        }

        float h[16];
#pragma unroll
        for (int j = 0; j < 8; ++j) {
            h[2 * j]     = hp[j].x;
            h[2 * j + 1] = hp[j].y;
        }

        // FMA from LDS weights (xor-swizzled, bank-uniform).
        float a0 = 0.f, a1 = 0.f, a2 = 0.f, a3 = 0.f;
#pragma unroll
        for (int gi = 0; gi < 4; ++gi) {
            float4 w0 = W[mybase + ((0 * 4 + gi) ^ lx)];
            float4 w1 = W[mybase + ((1 * 4 + gi) ^ lx)];
            float4 w2 = W[mybase + ((2 * 4 + gi) ^ lx)];
            float4 w3 = W[mybase + ((3 * 4 + gi) ^ lx)];
            const float h0v = h[gi * 4 + 0], h1v = h[gi * 4 + 1];
            const float h2v = h[gi * 4 + 2], h3v = h[gi * 4 + 3];
            a0 = fmaf(h0v, w0.x, a0); a0 = fmaf(h1v, w0.y, a0);
            a0 = fmaf(h2v, w0.z, a0); a0 = fmaf(h3v, w0.w, a0);
            a1 = fmaf(h0v, w1.x, a1); a1 = fmaf(h1v, w1.y, a1);
            a1 = fmaf(h2v, w1.z, a1); a1 = fmaf(h3v, w1.w, a1);
            a2 = fmaf(h0v, w2.x, a2); a2 = fmaf(h1v, w2.y, a2);
            a2 = fmaf(h2v, w2.z, a2); a2 = fmaf(h3v, w2.w, a2);
            a3 = fmaf(h0v, w3.x, a3); a3 = fmaf(h1v, w3.y, a3);
            a3 = fmaf(h2v, w3.z, a3); a3 = fmaf(h3v, w3.w, a3);
        }

        // Reduce over p (lane bits 1..5).
#pragma unroll
        for (int m = 2; m <= 32; m <<= 1) {
            a0 += __shfl_xor(a0, m, 64);
            a1 += __shfl_xor(a1, m, 64);
            a2 += __shfl_xor(a2, m, 64);
            a3 += __shfl_xor(a3, m, 64);
        }

        float hval = 0.f;
        if (lane < 2) {
            float yi = xpi + a0;
            float yf = xpf + a1;
            float yg = xpg + a2;
            float yo = xpo + a3;
            float si = fast_sig(yi);
            float sf = fast_sig(yf);
            float so = fast_sig(yo);
            float tg = fast_tanh(yg);
            c_val = fmaf(sf, c_val, si * tg);
            hval  = so * fast_tanh(c_val);
        }
        const float h_other = __shfl_xor(hval, 1, 64);  // partner d's h

        // Publish FIRST (critical path), out store after. Lanes 0/1 each
        // write 4 replicas at the permuted slot.
        if (lane < 2) {
            f32x4 pub;
            pub.x = (lane == 0) ? hval : h_other;
            pub.y = (lane == 0) ? h_other : hval;
            pub.z = (float)t;
            pub.w = 0.0f;
            f32x4* dst = hb + (size_t)(lane * 4) * 512 + (t & 1) * 256 + pfj;
            store_cohere(dst + 0 * 512, pub);
            store_cohere(dst + 1 * 512, pub);
            store_cohere(dst + 2 * 512, pub);
            store_cohere(dst + 3 * 512, pub);
        }

        if (lane == 0)
            *(float2*)(out + (size_t)t * LSTM_D + d0) = make_float2(hval, h_other);
    }

    if (lane < 2) cbuf[d] = c_val;   // c carry for next chunk launch
}

// ---------------------------------------------------------------------------
extern "C" void kernel_launch(void* const* d_in, const int* in_sizes, int n_in,
                              void* d_out, int out_size, void* d_ws, size_t ws_size,
                              hipStream_t stream)
{
    const float* xs = (const float*)d_in[0];   // [L, 512]
    const float* Wi = (const float*)d_in[1];   // [512, 2048]
    const float* Wh = (const float*)d_in[2];   // [512, 2048]
    const float* b  = (const float*)d_in[3];   // [2048]
    const float* c0 = (const float*)d_in[4];   // [512]
    const float* h0 = (const float*)d_in[5];   // [512]
    float* out = (float*)d_out;                // [L, 512]

    uint8_t* ws = (uint8_t*)d_ws;
    f32x4*  hb    = (f32x4*)ws;
    float*  cbuf  = (float*)(ws + WS_CBUF_OFF);
    float4* wpack = (float4*)(ws + WS_WPACK_OFF);
    float*  xbuf  = (float*)(ws + WS_XBUF_OFF);

    // Largest power-of-two chunk whose xbuf fits in the workspace.
    int C = LSTM_L;
    while (C > 64 &&
           WS_XBUF_OFF + (size_t)C * LSTM_4D * sizeof(float) > ws_size)
        C >>= 1;

    init_h<<<N_REPL, 256, 0, stream>>>(h0, hb);
    pack_wh<<<REC_G, 256, 0, stream>>>(Wh, wpack);

    const int nChunks = LSTM_L / C;
    for (int k = 0; k < nChunks; ++k) {
        dim3 ggrid(LSTM_4D / 64, C / 64);
        gemm_xproj<<<ggrid, 256, 0, stream>>>(xs + (size_t)k * C * LSTM_D,
                                              Wi, b, xbuf);
        lstm_rec<<<REC_G, 256, 0, stream>>>(wpack, xbuf, c0, out,
                                            hb, cbuf, k * C, C);
    }
}

// Round 15
// 52123.859 us; speedup vs baseline: 1.8924x; 1.0838x over previous
//
#include <hip/hip_runtime.h>
#include <cstdint>
#include <cstddef>

#define LSTM_D  512
#define LSTM_4D 2048
#define LSTM_L  32768
#define REC_G   64               // workgroups; each owns 8 d-indices
#define REC_DPW 8
#define N_REPL  8                // h-buffer replicas (channel spreading)

typedef float f32x4 __attribute__((ext_vector_type(4)));  // native v4f32 for asm "v"

// Workspace layout:
//   ws +      0 : hb, 8 replicas x (2 buffers x 256 f32x4) = 64 KB
//                 replica r, buffer B, PHYSICAL slot s at hb[r*512 + B*256 + s]
//                 Logical flit f = {h[2f], h[2f+1], tag, 0} lives at physical
//                 slot phys(f) = (f&7)*32 + (f>>3).  Instruction-contiguous
//                 permutation: consumer spin-load instruction j reads slots
//                 j*32..j*32+31 = 512 B contiguous = 4 lines.
//   ws +  65536 : cbuf (512 f) c carry between chunk launches
//   ws + 131072 : wpack (64 wg * 4096 float4 = 4 MB) swizzled Wh
//   ws + 131072 + 4 MB : xbuf (C*2048 f) x-projection chunk (r3 row layout)
#define WS_CBUF_OFF  65536
#define WS_WPACK_OFF 131072
#define WS_XBUF_OFF  (131072 + (size_t)REC_G * 4096 * sizeof(float4))

// ---------------------------------------------------------------------------
// GEMM: xbuf[C][2048] = xs_chunk[C][512] @ Wi[512][2048] + b
// EXACT r3 version (coalesced float4 stores, plain row layout).
// ---------------------------------------------------------------------------
__global__ __launch_bounds__(256)
void gemm_xproj(const float* __restrict__ A,
                const float* __restrict__ B,
                const float* __restrict__ bias,
                float* __restrict__ C)
{
    __shared__ float As[16][64];
    __shared__ float Bs[16][64];
    const int tid  = threadIdx.x;
    const int row0 = blockIdx.y * 64;
    const int col0 = blockIdx.x * 64;
    const int tx   = tid & 15;
    const int ty   = tid >> 4;
    const int lr   = tid >> 2;
    const int lk4  = (tid & 3) * 4;
    const int bk   = tid >> 4;
    const int bc4  = (tid & 15) * 4;

    float acc[4][4] = {};

    for (int k0 = 0; k0 < LSTM_D; k0 += 16) {
        float4 av = *(const float4*)(A + (size_t)(row0 + lr) * LSTM_D + k0 + lk4);
        float4 bv = *(const float4*)(B + (size_t)(k0 + bk) * LSTM_4D + col0 + bc4);
        __syncthreads();
        As[lk4 + 0][lr] = av.x;
        As[lk4 + 1][lr] = av.y;
        As[lk4 + 2][lr] = av.z;
        As[lk4 + 3][lr] = av.w;
        *(float4*)(&Bs[bk][bc4]) = bv;
        __syncthreads();
#pragma unroll
        for (int k = 0; k < 16; ++k) {
            float4 a4 = *(const float4*)(&As[k][ty * 4]);
            float4 b4 = *(const float4*)(&Bs[k][tx * 4]);
            acc[0][0] = fmaf(a4.x, b4.x, acc[0][0]);
            acc[0][1] = fmaf(a4.x, b4.y, acc[0][1]);
            acc[0][2] = fmaf(a4.x, b4.z, acc[0][2]);
            acc[0][3] = fmaf(a4.x, b4.w, acc[0][3]);
            acc[1][0] = fmaf(a4.y, b4.x, acc[1][0]);
            acc[1][1] = fmaf(a4.y, b4.y, acc[1][1]);
            acc[1][2] = fmaf(a4.y, b4.z, acc[1][2]);
            acc[1][3] = fmaf(a4.y, b4.w, acc[1][3]);
            acc[2][0] = fmaf(a4.z, b4.x, acc[2][0]);
            acc[2][1] = fmaf(a4.z, b4.y, acc[2][1]);
            acc[2][2] = fmaf(a4.z, b4.z, acc[2][2]);
            acc[2][3] = fmaf(a4.z, b4.w, acc[2][3]);
            acc[3][0] = fmaf(a4.w, b4.x, acc[3][0]);
            acc[3][1] = fmaf(a4.w, b4.y, acc[3][1]);
            acc[3][2] = fmaf(a4.w, b4.z, acc[3][2]);
            acc[3][3] = fmaf(a4.w, b4.w, acc[3][3]);
        }
    }

    float4 bb = *(const float4*)(bias + col0 + tx * 4);
#pragma unroll
    for (int i = 0; i < 4; ++i) {
        float4 o;
        o.x = acc[i][0] + bb.x;
        o.y = acc[i][1] + bb.y;
        o.z = acc[i][2] + bb.z;
        o.w = acc[i][3] + bb.w;
        *(float4*)(C + (size_t)(row0 + ty * 4 + i) * LSTM_4D + col0 + tx * 4) = o;
    }
}

// ---------------------------------------------------------------------------
// Swizzled Wh pack (unchanged; see lstm_rec layout comment).
// ---------------------------------------------------------------------------
__global__ __launch_bounds__(256)
void pack_wh(const float* __restrict__ Wh, float4* __restrict__ wp)
{
    const int wg  = blockIdx.x;
    const int tid = threadIdx.x;
    for (int s = 0; s < 16; ++s) {
        const int gidx  = s * 256 + tid;
        const int wave  = gidx >> 10;
        const int lane  = (gidx >> 4) & 63;
        const int mphys = gidx & 15;
        const int m     = mphys ^ (lane & 15);
        const int g     = m >> 2;
        const int gi    = m & 3;
        const int p     = lane >> 1;
        const int d     = wg * REC_DPW + wave * 2 + (lane & 1);
        const int k     = p * 16 + gi * 4;
        float4 v;
        v.x = Wh[(size_t)(k + 0) * LSTM_4D + g * LSTM_D + d];
        v.y = Wh[(size_t)(k + 1) * LSTM_4D + g * LSTM_D + d];
        v.z = Wh[(size_t)(k + 2) * LSTM_4D + g * LSTM_D + d];
        v.w = Wh[(size_t)(k + 3) * LSTM_4D + g * LSTM_D + d];
        wp[(size_t)wg * 4096 + gidx] = v;
    }
}

// ---------------------------------------------------------------------------
// Init tagged h replicas in the PERMUTED layout. Buffer 1 = h0 with tag -1
// (step 0 reads buffer (0-1)&1 = 1 expecting tag -1); buffer 0 tag = -2.
// Logical flit j lands at physical slot (j&7)*32 + (j>>3).
// ---------------------------------------------------------------------------
__global__ void init_h(const float* __restrict__ h0, f32x4* __restrict__ hb)
{
    const int r = blockIdx.x;                // replica 0..7
    const int j = threadIdx.x;               // logical flit 0..255
    const int s = (j & 7) * 32 + (j >> 3);   // physical slot
    f32x4 a; a.x = h0[2 * j]; a.y = h0[2 * j + 1]; a.z = -1.0f; a.w = 0.0f;
    f32x4 z; z.x = 0.0f;      z.y = 0.0f;          z.z = -2.0f; z.w = 0.0f;
    hb[r * 512 + 256 + s] = a;
    hb[r * 512 + s]       = z;
}

// ---------------------------------------------------------------------------
// Coherent 16B ops straight to/from the coherence point (sc0 sc1 bypass
// L1/L2): tag travels in the same 16B flit as the data.  r3-verified form:
// vmcnt(0) inside every poll -- no loads ever left in flight (r5 lesson).
// NOTE: waits vmcnt only; outstanding lgkmcnt (weight ds_reads) is NOT
// drained here -- that is the r12 overlap.
// ---------------------------------------------------------------------------
__device__ inline void load8_cohere(const f32x4* p, f32x4 h[8])
{
    asm volatile(
        "global_load_dwordx4 %0, %8, off sc0 sc1\n\t"
        "global_load_dwordx4 %1, %8, off offset:512 sc0 sc1\n\t"
        "global_load_dwordx4 %2, %8, off offset:1024 sc0 sc1\n\t"
        "global_load_dwordx4 %3, %8, off offset:1536 sc0 sc1\n\t"
        "global_load_dwordx4 %4, %8, off offset:2048 sc0 sc1\n\t"
        "global_load_dwordx4 %5, %8, off offset:2560 sc0 sc1\n\t"
        "global_load_dwordx4 %6, %8, off offset:3072 sc0 sc1\n\t"
        "global_load_dwordx4 %7, %8, off offset:3584 sc0 sc1\n\t"
        "s_waitcnt vmcnt(0)"
        : "=&v"(h[0]), "=&v"(h[1]), "=&v"(h[2]), "=&v"(h[3]),
          "=&v"(h[4]), "=&v"(h[5]), "=&v"(h[6]), "=&v"(h[7])
        : "v"(p)
        : "memory");
}

__device__ inline void store_cohere(f32x4* p, f32x4 v)
{
    asm volatile("global_store_dwordx4 %0, %1, off sc0 sc1"
                 :: "v"(p), "v"(v) : "memory");
}

// r12: explicit LDS weight read, issued BEFORE the spin (volatile asm keeps
// program order vs the spin's volatile asm), left outstanding on lgkmcnt
// while the spin waits on vmcnt only. The ~770 cyc of per-CU LDS pipe time
// (4 waves x 16 ds_read_b128) thus executes under the spin's dead time
// instead of after detection.
__device__ inline void lds_read_b128(unsigned addr, f32x4* v)
{
    asm volatile("ds_read_b128 %0, %1" : "=&v"(*v) : "v"(addr));
}

// Post-detect join: drain lgkmcnt, tie all 16 weight quads so the FMA
// cannot be hoisted above the wait (rule #18: hipcc moves register-only
// ops past asm waitcnt; data-dependence tie + sched_barrier(0) stops it).
__device__ inline void lds_join16(f32x4 wv[16])
{
    asm volatile("s_waitcnt lgkmcnt(0)"
                 : "+v"(wv[0]), "+v"(wv[1]), "+v"(wv[2]), "+v"(wv[3]),
                   "+v"(wv[4]), "+v"(wv[5]), "+v"(wv[6]), "+v"(wv[7]),
                   "+v"(wv[8]), "+v"(wv[9]), "+v"(wv[10]), "+v"(wv[11]),
                   "+v"(wv[12]), "+v"(wv[13]), "+v"(wv[14]), "+v"(wv[15])
                 :: "memory");
    __builtin_amdgcn_sched_barrier(0);
}

// Fast activations: v_exp + v_rcp forms (r11-verified WIN: 67.0 -> 56.5 ms,
// absmax 3.9e-3 unchanged, threshold 1.8e-2).
__device__ inline float fast_sig(float x)
{
    return __builtin_amdgcn_rcpf(1.0f + __expf(-x));
}
__device__ inline float fast_tanh(float x)
{
    return 1.0f - 2.0f * __builtin_amdgcn_rcpf(1.0f + __expf(2.0f * x));
}

// ---------------------------------------------------------------------------
// Barrier-free persistent recurrent kernel.
//
// r12-resubmit x3 (broker timeouts) = r11 (56.5 ms verified best) + ONE
// change: weight LDS reads hoisted ABOVE the tagged spin as volatile-asm
// ds_read_b128 with the lgkmcnt drain AFTER detection. h-independent work
// moves off the post-detect critical segment. wv[] live range is a single
// iteration (not loop-carried), so this does not recreate the r7 spill
// problem; destinations are tied at the join before use and reused only
// after this iteration's lgkmcnt(0) retired them (no r5 hazard).
// Spin protocol unchanged: tag-in-flit self-validating, vmcnt(0) per poll,
// 8 replicas, permuted slots, publish-first. Buffer reuse safety: a wave
// publishes t only after consuming t-1, so all-t-tags visible implies all
// t-1 reads retired.
// ---------------------------------------------------------------------------
__global__ __launch_bounds__(256, 1)
void lstm_rec(const float4* __restrict__ wp,
              const float* __restrict__ xp,    // chunk's [steps][2048] row layout
              const float* __restrict__ c0,
              float* __restrict__ out,
              f32x4* __restrict__ hb,          // 8 x 2 x 256 tagged pairs
              float* __restrict__ cbuf,        // 512 floats
              int t0, int steps)
{
    __shared__ float4 W[4096];                 // exactly 64 KB

    const int wg   = blockIdx.x;
    const int tid  = threadIdx.x;
    const int wave = tid >> 6;
    const int lane = tid & 63;
    const int p    = lane >> 1;
    const int d    = wg * REC_DPW + wave * 2 + (lane & 1);
    const int d0   = wg * REC_DPW + wave * 2;  // wave's first d
    const int mybase = wave * 1024 + lane * 16;
    const int lx   = lane & 15;
    const int fj   = wg * 4 + wave;            // this wave's logical flit
    const int pfj  = (fj & 7) * 32 + (fj >> 3);// physical slot of that flit
    const int myrep = wg & 7;                  // consumer replica

    // One-time LDS weight fill (coalesced 64 KB copy), the only barrier.
#pragma unroll
    for (int s = 0; s < 16; ++s)
        W[s * 256 + tid] = wp[(size_t)wg * 4096 + s * 256 + tid];
    __syncthreads();

    // Loop-invariant per-lane LDS byte addresses of the 16 weight quads
    // (xor-swizzled, bank-uniform -- same addresses the r11 C++ loads used).
    const unsigned wlds = (unsigned)(uintptr_t)&W[mybase];
    unsigned waddr[16];
#pragma unroll
    for (int m = 0; m < 16; ++m)
        waddr[m] = wlds + ((unsigned)(m ^ lx) << 4);

    float c_val = 0.f;
    if (lane < 2) c_val = (t0 == 0) ? c0[d] : cbuf[d];

    int dead = 0;

    for (int ts = 0; ts < steps; ++ts) {
        const int t = t0 + ts;

        // Weight prefetch: 16 ds_read_b128 issued NOW, drained after the
        // spin. The LDS pipe works during the spin's dead time.
        f32x4 wv[16];
#pragma unroll
        for (int m = 0; m < 16; ++m)
            lds_read_b128(waddr[m], &wv[m]);

        // xp prefetch (independent of h), lanes 0/1 only.
        float xpi = 0.f, xpf = 0.f, xpg = 0.f, xpo = 0.f;
        if (lane < 2) {
            const float* row = xp + (size_t)ts * LSTM_4D + d;
            xpi = row[0];
            xpf = row[LSTM_D];
            xpg = row[2 * LSTM_D];
            xpo = row[3 * LSTM_D];
        }

        // Tagged spin-consume from replica wg&7, buffer (t-1)&1. Waits
        // vmcnt only; weight ds_reads stay outstanding on lgkmcnt.
        const float  exp_tag = (float)(t - 1);
        const f32x4* src = hb + myrep * 512 + ((t + 1) & 1) * 256 + p;
        f32x4 hp[8];
        int tries = 0;
        for (;;) {
            load8_cohere(src, hp);
            bool ok = (hp[0].z == exp_tag) & (hp[1].z == exp_tag) &
                      (hp[2].z == exp_tag) & (hp[3].z == exp_tag) &
                      (hp[4].z == exp_tag) & (hp[5].z == exp_tag) &
                      (hp[6].z == exp_tag) & (hp[7].z == exp_tag);
            if (dead || (__ballot(ok) == ~0ull)) break;
            if (++tries > (1 << 16)) { dead = 1; break; }
        }

        // Join the weight prefetch (lgkmcnt 0 + tie + sched fence).
        lds_join16(wv);

        float h[16];
#pragma unroll
        for (int j = 0; j < 8; ++j) {
            h[2 * j]     = hp[j].x;
            h[2 * j + 1] = hp[j].y;
        }

        // FMA from register-resident weight quads (prefetched from LDS).
        float a0 = 0.f, a1 = 0.f, a2 = 0.f, a3 = 0.f;
#pragma unroll
        for (int gi = 0; gi < 4; ++gi) {
            const f32x4 w0 = wv[0 * 4 + gi];
            const f32x4 w1 = wv[1 * 4 + gi];
            const f32x4 w2 = wv[2 * 4 + gi];
            const f32x4 w3 = wv[3 * 4 + gi];
            const float h0v = h[gi * 4 + 0], h1v = h[gi * 4 + 1];
            const float h2v = h[gi * 4 + 2], h3v = h[gi * 4 + 3];
            a0 = fmaf(h0v, w0.x, a0); a0 = fmaf(h1v, w0.y, a0);
            a0 = fmaf(h2v, w0.z, a0); a0 = fmaf(h3v, w0.w, a0);
            a1 = fmaf(h0v, w1.x, a1); a1 = fmaf(h1v, w1.y, a1);
            a1 = fmaf(h2v, w1.z, a1); a1 = fmaf(h3v, w1.w, a1);
            a2 = fmaf(h0v, w2.x, a2); a2 = fmaf(h1v, w2.y, a2);
            a2 = fmaf(h2v, w2.z, a2); a2 = fmaf(h3v, w2.w, a2);
            a3 = fmaf(h0v, w3.x, a3); a3 = fmaf(h1v, w3.y, a3);
            a3 = fmaf(h2v, w3.z, a3); a3 = fmaf(h3v, w3.w, a3);
        }

        // Reduce over p (lane bits 1..5).
#pragma unroll
        for (int m = 2; m <= 32; m <<= 1) {
            a0 += __shfl_xor(a0, m, 64);
            a1 += __shfl_xor(a1, m, 64);
            a2 += __shfl_xor(a2, m, 64);
            a3 += __shfl_xor(a3, m, 64);
        }

        float hval = 0.f;
        if (lane < 2) {
            float yi = xpi + a0;
            float yf = xpf + a1;
            float yg = xpg + a2;
            float yo = xpo + a3;
            float si = fast_sig(yi);
            float sf = fast_sig(yf);
            float so = fast_sig(yo);
            float tg = fast_tanh(yg);
            c_val = fmaf(sf, c_val, si * tg);
            hval  = so * fast_tanh(c_val);
        }
        const float h_other = __shfl_xor(hval, 1, 64);  // partner d's h

        // Publish FIRST (critical path), out store after. Lanes 0/1 each
        // write 4 replicas at the permuted slot.
        if (lane < 2) {
            f32x4 pub;
            pub.x = (lane == 0) ? hval : h_other;
            pub.y = (lane == 0) ? h_other : hval;
            pub.z = (float)t;
            pub.w = 0.0f;
            f32x4* dst = hb + (size_t)(lane * 4) * 512 + (t & 1) * 256 + pfj;
            store_cohere(dst + 0 * 512, pub);
            store_cohere(dst + 1 * 512, pub);
            store_cohere(dst + 2 * 512, pub);
            store_cohere(dst + 3 * 512, pub);
        }

        if (lane == 0)
            *(float2*)(out + (size_t)t * LSTM_D + d0) = make_float2(hval, h_other);
    }

    if (lane < 2) cbuf[d] = c_val;   // c carry for next chunk launch
}

// ---------------------------------------------------------------------------
extern "C" void kernel_launch(void* const* d_in, const int* in_sizes, int n_in,
                              void* d_out, int out_size, void* d_ws, size_t ws_size,
                              hipStream_t stream)
{
    const float* xs = (const float*)d_in[0];   // [L, 512]
    const float* Wi = (const float*)d_in[1];   // [512, 2048]
    const float* Wh = (const float*)d_in[2];   // [512, 2048]
    const float* b  = (const float*)d_in[3];   // [2048]
    const float* c0 = (const float*)d_in[4];   // [512]
    const float* h0 = (const float*)d_in[5];   // [512]
    float* out = (float*)d_out;                // [L, 512]

    uint8_t* ws = (uint8_t*)d_ws;
    f32x4*  hb    = (f32x4*)ws;
    float*  cbuf  = (float*)(ws + WS_CBUF_OFF);
    float4* wpack = (float4*)(ws + WS_WPACK_OFF);
    float*  xbuf  = (float*)(ws + WS_XBUF_OFF);

    // Largest power-of-two chunk whose xbuf fits in the workspace.
    int C = LSTM_L;
    while (C > 64 &&
           WS_XBUF_OFF + (size_t)C * LSTM_4D * sizeof(float) > ws_size)
        C >>= 1;

    init_h<<<N_REPL, 256, 0, stream>>>(h0, hb);
    pack_wh<<<REC_G, 256, 0, stream>>>(Wh, wpack);

    const int nChunks = LSTM_L / C;
    for (int k = 0; k < nChunks; ++k) {
        dim3 ggrid(LSTM_4D / 64, C / 64);
        gemm_xproj<<<ggrid, 256, 0, stream>>>(xs + (size_t)k * C * LSTM_D,
                                              Wi, b, xbuf);
        lstm_rec<<<REC_G, 256, 0, stream>>>(wpack, xbuf, c0, out,
                                            hb, cbuf, k * C, C);
    }
}